// Round 7
// baseline (4216.621 us; speedup 1.0000x reference)
//
#include <hip/hip_runtime.h>
#include <hip/hip_bf16.h>

#define NN   13824     // 24^3 neurons
#define BB   256       // batch
#define KDIM 512       // input dim
#define ODIM 1000      // output dim
#define CUBE 24
#define KS   16        // out-gemm split-K
#define PBLK 512       // persistent grid blocks (2/CU guaranteed via launch_bounds)

typedef short bf8 __attribute__((ext_vector_type(8)));     // 8 bf16 (4 VGPRs)
typedef float f32x4 __attribute__((ext_vector_type(4)));   // MFMA acc

__device__ __forceinline__ float fast_tanh(float a) {
    float e = __expf(2.0f * a);
    return 1.0f - 2.0f / (e + 1.0f);
}
__device__ __forceinline__ float bf_lo(unsigned u) { return __uint_as_float(u << 16); }
__device__ __forceinline__ float bf_hi(unsigned u) { return __uint_as_float(u & 0xffff0000u); }
__device__ __forceinline__ unsigned short bf_rne(float f) {
    unsigned u = __float_as_uint(f);
    u += 0x7fffu + ((u >> 16) & 1u);
    return (unsigned short)(u >> 16);
}
__device__ __forceinline__ unsigned pk_bf16(float lo, float hi) {
    union { __hip_bfloat162 h; unsigned u; } cv;
    cv.h = __float22bfloat162_rn(make_float2(lo, hi));
    return cv.u;
}
__device__ __forceinline__ bf8 cvt8(float4 a, float4 b) {
    union { bf8 v; unsigned u[4]; } r;
    r.u[0] = pk_bf16(a.x, a.y);
    r.u[1] = pk_bf16(a.z, a.w);
    r.u[2] = pk_bf16(b.x, b.y);
    r.u[3] = pk_bf16(b.z, b.w);
    return r.v;
}

// ---------------------------------------------------------------------------
// x (fp32 [256][512]) -> x_bf (bf16 packed dwords)
// ---------------------------------------------------------------------------
__global__ __launch_bounds__(256) void xbf_kernel(
    const float* __restrict__ x, unsigned* __restrict__ xb)
{
    int i = blockIdx.x * 256 + threadIdx.x;
    float2 v = *(const float2*)&x[(size_t)i * 2];
    xb[i] = pk_bf16(v.x, v.y);
}

// ---------------------------------------------------------------------------
// xproj via MFMA, software-pipelined, fused h1 = tanh(xp) epilogue.
// ---------------------------------------------------------------------------
__global__ __launch_bounds__(256) void xproj_mfma(
    const float* __restrict__ w_in, const float* __restrict__ bias,
    const short* __restrict__ xbf, unsigned short* __restrict__ xp,
    unsigned short* __restrict__ h1)
{
    const int tid = threadIdx.x, w = tid >> 6, lane = tid & 63;
    const int quad = lane >> 4, l16 = lane & 15;
    const int n0 = blockIdx.x * 16;
    const float* __restrict__ arow = &w_in[(size_t)(n0 + l16) * KDIM];

    f32x4 acc[4] = {};

    int ka = quad * 8;
    float4 a0 = *(const float4*)&arow[ka];
    float4 a1 = *(const float4*)&arow[ka + 4];
    bf8 bb[4];
#pragma unroll
    for (int j = 0; j < 4; ++j)
        bb[j] = *(const bf8*)&xbf[(size_t)(w * 64 + j * 16 + l16) * KDIM + ka];

    for (int it = 0; it < 16; ++it) {
        float4 na0{}, na1{}; bf8 nb[4] = {};
        if (it < 15) {
            const int nka = ka + 32;
            na0 = *(const float4*)&arow[nka];
            na1 = *(const float4*)&arow[nka + 4];
#pragma unroll
            for (int j = 0; j < 4; ++j)
                nb[j] = *(const bf8*)&xbf[(size_t)(w * 64 + j * 16 + l16) * KDIM + nka];
        }
        bf8 af = cvt8(a0, a1);
#pragma unroll
        for (int j = 0; j < 4; ++j)
            acc[j] = __builtin_amdgcn_mfma_f32_16x16x32_bf16(af, bb[j], acc[j], 0, 0, 0);
        a0 = na0; a1 = na1;
#pragma unroll
        for (int j = 0; j < 4; ++j) bb[j] = nb[j];
        ka += 32;
    }

#pragma unroll
    for (int j = 0; j < 4; ++j) {
        const int b = w * 64 + j * 16 + l16;
#pragma unroll
        for (int r = 0; r < 4; ++r) {
            const int n = n0 + quad * 4 + r;
            const float v = acc[j][r] + bias[n];
            xp[(size_t)n * BB + b] = bf_rne(v);
            h1[(size_t)n * BB + b] = bf_rne(fast_tanh(v));
        }
    }
}

// ---------------------------------------------------------------------------
// Persistent steps with a manual device-scope grid barrier.
// Grid PBLK=512 x 256thr, launch_bounds(256,2) -> 2 blocks/CU -> all resident.
// bid&7 = XCD z-slab. 4608 units total; wave 0 of each block takes 3 units.
// ---------------------------------------------------------------------------
__device__ __forceinline__ void grid_barrier(unsigned* bar, unsigned nblk)
{
    __syncthreads();                       // drains this block's stores to L2
    if (threadIdx.x == 0) {
        __threadfence();                   // agent release: L2 writeback to IC
        unsigned g = __hip_atomic_load(&bar[1], __ATOMIC_RELAXED, __HIP_MEMORY_SCOPE_AGENT);
        unsigned a = __hip_atomic_fetch_add(&bar[0], 1u, __ATOMIC_ACQ_REL, __HIP_MEMORY_SCOPE_AGENT);
        if (a == nblk - 1u) {
            __hip_atomic_store(&bar[0], 0u, __ATOMIC_RELAXED, __HIP_MEMORY_SCOPE_AGENT);
            __hip_atomic_fetch_add(&bar[1], 1u, __ATOMIC_RELEASE, __HIP_MEMORY_SCOPE_AGENT);
        } else {
            while (__hip_atomic_load(&bar[1], __ATOMIC_RELAXED, __HIP_MEMORY_SCOPE_AGENT) == g)
                __builtin_amdgcn_s_sleep(1);
        }
    }
    __syncthreads();
    __threadfence();                       // agent acquire: invalidate stale L1/L2
}

__device__ __forceinline__ void load_plane_f2(
    const unsigned* __restrict__ h32, int z, int y, int xx, int dof, float2* w9)
{
#pragma unroll
    for (int j = 0; j < 9; ++j) {
        const int dz = j / 3 - 1, dy = j % 3 - 1;
        const int zz = z + dz, yy = y + dy;
        const bool valid = (xx >= 0) & (xx < CUBE) & (zz >= 0) & (zz < CUBE) &
                           (yy >= 0) & (yy < CUBE);   // wave-uniform
        unsigned v = 0u;
        if (valid) v = h32[(size_t)((zz * 24 + yy) * 24 + xx) * 128 + dof];
        w9[j] = make_float2(bf_lo(v), bf_hi(v));
    }
}

__device__ __forceinline__ void step_unit(
    const unsigned* __restrict__ hprev, const unsigned* __restrict__ xp,
    const float* __restrict__ wl, unsigned* __restrict__ hnext,
    int z, int y, int x0, int dof)
{
    float2 win[5][9];
    load_plane_f2(hprev, z, y, x0 - 1, dof, win[0]);
    load_plane_f2(hprev, z, y, x0,     dof, win[1]);
    load_plane_f2(hprev, z, y, x0 + 1, dof, win[2]);
    load_plane_f2(hprev, z, y, x0 + 2, dof, win[3]);

#pragma unroll
    for (int xi = 0; xi < 6; ++xi) {
        const int x = x0 + xi;
        if (xi <= 3)
            load_plane_f2(hprev, z, y, x + 3, dof, win[(xi + 4) % 5]);

        const int n = (z * 24 + y) * 24 + x;          // wave-uniform
        const float* __restrict__ wn = &wl[(size_t)n * 27];
        const unsigned xpv = xp[(size_t)n * 128 + dof];

        const float2* pm = win[xi % 5];
        const float2* pc = win[(xi + 1) % 5];
        const float2* pp = win[(xi + 2) % 5];

        float2 a0 = make_float2(bf_lo(xpv), bf_hi(xpv));
        float2 a1 = make_float2(0.f, 0.f);
        float2 a2 = make_float2(0.f, 0.f);
#pragma unroll
        for (int jy = 0; jy < 3; ++jy) {
            {
                const int j = jy;
                const float w0 = wn[3 * j], w1 = wn[3 * j + 1], w2 = wn[3 * j + 2];
                a0.x += w0 * pm[j].x + w1 * pc[j].x + w2 * pp[j].x;
                a0.y += w0 * pm[j].y + w1 * pc[j].y + w2 * pp[j].y;
            }
            {
                const int j = 3 + jy;
                const float w0 = wn[3 * j], w1 = wn[3 * j + 1], w2 = wn[3 * j + 2];
                a1.x += w0 * pm[j].x + w1 * pc[j].x + w2 * pp[j].x;
                a1.y += w0 * pm[j].y + w1 * pc[j].y + w2 * pp[j].y;
            }
            {
                const int j = 6 + jy;
                const float w0 = wn[3 * j], w1 = wn[3 * j + 1], w2 = wn[3 * j + 2];
                a2.x += w0 * pm[j].x + w1 * pc[j].x + w2 * pp[j].x;
                a2.y += w0 * pm[j].y + w1 * pc[j].y + w2 * pp[j].y;
            }
        }
        hnext[(size_t)n * 128 + dof] =
            pk_bf16(fast_tanh(a0.x + a1.x + a2.x), fast_tanh(a0.y + a1.y + a2.y));
    }
}

__global__ __launch_bounds__(256, 2) void steps_persistent(
    unsigned* __restrict__ hA, unsigned* __restrict__ hB,
    const unsigned* __restrict__ xp, const float* __restrict__ wl,
    unsigned* bar)
{
    const int tid  = threadIdx.x;
    const int wv   = __builtin_amdgcn_readfirstlane(tid >> 6);
    const int lane = tid & 63;

    const int bid  = blockIdx.x;          // 0..511
    const int zhi  = bid & 7;             // XCD slab: z in [zhi*3, zhi*3+3)
    const int sbid = bid >> 3;            // 0..63 within slab
    const int wis  = sbid * 4 + wv;       // wave-in-slab 0..255

    // units u in [0,576) per slab: y=u%24; r=u/24: xc=r&3, rr=r>>2, zlo=rr%3, bh=rr/3
    const int nu = (wv == 0) ? 3 : 2;
    int zl[3], yl[3], x0l[3], dofl[3];
#pragma unroll
    for (int k = 0; k < 3; ++k) {
        int u = (k < 2) ? (wis + k * 256) : (512 + sbid);
        const int y  = u % 24;
        const int r  = u / 24;            // 0..23
        const int xc  = r & 3;
        const int rr  = r >> 2;           // 0..5
        const int zlo = rr % 3;
        const int bh  = rr / 3;
        zl[k]   = zhi * 3 + zlo;
        yl[k]   = y;
        x0l[k]  = xc * 6;
        dofl[k] = bh * 64 + lane;
    }

    const unsigned* cur = hA;
    unsigned*       nxt = hB;
#pragma unroll 1
    for (int s = 0; s < 29; ++s) {
        step_unit(cur, xp, wl, nxt, zl[0], yl[0], x0l[0], dofl[0]);
        step_unit(cur, xp, wl, nxt, zl[1], yl[1], x0l[1], dofl[1]);
        if (nu == 3)
            step_unit(cur, xp, wl, nxt, zl[2], yl[2], x0l[2], dofl[2]);
        if (s < 28) grid_barrier(bar, PBLK);
        const unsigned* t = cur; cur = nxt; nxt = (unsigned*)t;
    }
    // 29 steps from h1 in hA -> final state in hB
}

// ---------------------------------------------------------------------------
// Transpose h[k][b] -> hT[b][k] (bf16), 64x64 tiles via LDS.
// ---------------------------------------------------------------------------
__global__ __launch_bounds__(256) void transpose_kernel(
    const unsigned* __restrict__ h32, unsigned* __restrict__ hT32)
{
    __shared__ unsigned short T[64][66];
    const int tid = threadIdx.x;
    const int rr = tid >> 2, g = tid & 3;
    const int k0 = blockIdx.x * 64, b0 = blockIdx.y * 64;
#pragma unroll
    for (int i = 0; i < 8; ++i) {
        unsigned d = h32[(size_t)(k0 + rr) * 128 + b0 / 2 + g * 8 + i];
        const int bl = (g * 8 + i) * 2;
        T[bl][rr]     = (unsigned short)(d & 0xffffu);
        T[bl + 1][rr] = (unsigned short)(d >> 16);
    }
    __syncthreads();
#pragma unroll
    for (int i = 0; i < 8; ++i) {
        const int kl = (g * 8 + i) * 2;
        unsigned d = (unsigned)T[rr][kl] | ((unsigned)T[rr][kl + 1] << 16);
        hT32[(size_t)(b0 + rr) * (NN / 2) + k0 / 2 + g * 8 + i] = d;
    }
}

// ---------------------------------------------------------------------------
// Output GEMM via MFMA, split-K=16, software-pipelined (prefetch dist 1).
// ---------------------------------------------------------------------------
__global__ __launch_bounds__(256) void outgemm_mfma(
    const float* __restrict__ wout, const short* __restrict__ hT,
    float* __restrict__ part)
{
    const int tid = threadIdx.x, w = tid >> 6, lane = tid & 63;
    const int quad = lane >> 4, l16 = lane & 15;
    const int o0 = blockIdx.x * 32;
    const int kb = blockIdx.y * (NN / KS);
    const int b0 = w * 64;

    const int oa = o0 + l16, ob = o0 + 16 + l16;
    const bool av0 = oa < ODIM, av1 = ob < ODIM;
    const float* __restrict__ ar0 = &wout[(size_t)oa * NN];
    const float* __restrict__ ar1 = &wout[(size_t)ob * NN];
    const float4 z4 = {0.f, 0.f, 0.f, 0.f};

    f32x4 acc[2][4] = {};

    int ka = kb + quad * 8;
    float4 a00 = av0 ? *(const float4*)&ar0[ka]     : z4;
    float4 a01 = av0 ? *(const float4*)&ar0[ka + 4] : z4;
    float4 a10 = av1 ? *(const float4*)&ar1[ka]     : z4;
    float4 a11 = av1 ? *(const float4*)&ar1[ka + 4] : z4;
    bf8 bb[4];
#pragma unroll
    for (int j = 0; j < 4; ++j)
        bb[j] = *(const bf8*)&hT[(size_t)(b0 + j * 16 + l16) * NN + ka];

    for (int it = 0; it < 27; ++it) {
        float4 na00{}, na01{}, na10{}, na11{}; bf8 nb[4] = {};
        if (it < 26) {
            const int nka = ka + 32;
            na00 = av0 ? *(const float4*)&ar0[nka]     : z4;
            na01 = av0 ? *(const float4*)&ar0[nka + 4] : z4;
            na10 = av1 ? *(const float4*)&ar1[nka]     : z4;
            na11 = av1 ? *(const float4*)&ar1[nka + 4] : z4;
#pragma unroll
            for (int j = 0; j < 4; ++j)
                nb[j] = *(const bf8*)&hT[(size_t)(b0 + j * 16 + l16) * NN + nka];
        }
        bf8 af0 = cvt8(a00, a01);
        bf8 af1 = cvt8(a10, a11);
#pragma unroll
        for (int j = 0; j < 4; ++j) {
            acc[0][j] = __builtin_amdgcn_mfma_f32_16x16x32_bf16(af0, bb[j], acc[0][j], 0, 0, 0);
            acc[1][j] = __builtin_amdgcn_mfma_f32_16x16x32_bf16(af1, bb[j], acc[1][j], 0, 0, 0);
        }
        a00 = na00; a01 = na01; a10 = na10; a11 = na11;
#pragma unroll
        for (int j = 0; j < 4; ++j) bb[j] = nb[j];
        ka += 32;
    }

#pragma unroll
    for (int i = 0; i < 2; ++i)
#pragma unroll
        for (int j = 0; j < 4; ++j) {
            const int b = b0 + j * 16 + l16;
#pragma unroll
            for (int r = 0; r < 4; ++r) {
                const int o = o0 + i * 16 + quad * 4 + r;
                part[((size_t)blockIdx.y * 1024 + o) * BB + b] = acc[i][j][r];
            }
        }
}

__global__ __launch_bounds__(256) void reduce_kernel(
    const float* __restrict__ part, const float* __restrict__ bias,
    float* __restrict__ out)
{
    const int o = blockIdx.x, b = threadIdx.x;
    float s = bias[o];
#pragma unroll
    for (int kc = 0; kc < KS; ++kc)
        s += part[((size_t)kc * 1024 + o) * BB + b];
    out[(size_t)b * ODIM + o] = s;
}

extern "C" void kernel_launch(void* const* d_in, const int* in_sizes, int n_in,
                              void* d_out, int out_size, void* d_ws, size_t ws_size,
                              hipStream_t stream)
{
    const float* x       = (const float*)d_in[0];
    const float* w_in    = (const float*)d_in[1];
    const float* b_in    = (const float*)d_in[2];
    const float* w_local = (const float*)d_in[3];
    const float* w_out   = (const float*)d_in[4];
    const float* b_out   = (const float*)d_in[5];
    float* out = (float*)d_out;

    char* p = (char*)d_ws;
    unsigned short* xp_bf = (unsigned short*)p;          p += (size_t)NN * BB * 2;
    unsigned short* hA    = (unsigned short*)p;          p += (size_t)NN * BB * 2;
    unsigned short* hB    = (unsigned short*)p;          p += (size_t)NN * BB * 2;
    unsigned short* hT    = (unsigned short*)p;          p += (size_t)NN * BB * 2;
    unsigned short* x_bf  = (unsigned short*)p;          p += (size_t)BB * KDIM * 2;
    float*          part  = (float*)p;                   p += (size_t)KS * 1024 * BB * 4;
    unsigned*       bar   = (unsigned*)p;                // 2 dwords (cnt, gen)

    hipMemsetAsync((void*)bar, 0, 2 * sizeof(unsigned), stream);

    xbf_kernel<<<256, 256, 0, stream>>>(x, (unsigned*)x_bf);
    xproj_mfma<<<864, 256, 0, stream>>>(w_in, b_in, (const short*)x_bf, xp_bf, hA);

    steps_persistent<<<PBLK, 256, 0, stream>>>(
        (unsigned*)hA, (unsigned*)hB, (const unsigned*)xp_bf, w_local, bar);

    // final state in hB
    transpose_kernel<<<dim3(216, 4), 256, 0, stream>>>((const unsigned*)hB, (unsigned*)hT);
    outgemm_mfma<<<dim3(32, KS), 256, 0, stream>>>(w_out, (const short*)hT, part);
    reduce_kernel<<<ODIM, 256, 0, stream>>>(part, b_out, out);
}

// Round 8
// 4095.843 us; speedup vs baseline: 1.0295x; 1.0295x over previous
//
#include <hip/hip_runtime.h>
#include <hip/hip_bf16.h>

#define NN   13824     // 24^3 neurons
#define BB   256       // batch
#define KDIM 512       // input dim
#define ODIM 1000      // output dim
#define CUBE 24
#define KS   16        // out-gemm split-K
#define PBLK 1152      // persistent grid blocks; launch_bounds(256,5) -> 5 blocks/CU cap >= 4.5 needed

typedef short bf8 __attribute__((ext_vector_type(8)));     // 8 bf16 (4 VGPRs)
typedef float f32x4 __attribute__((ext_vector_type(4)));   // MFMA acc
typedef float f2v  __attribute__((ext_vector_type(2)));    // packed fp32 pair -> v_pk_fma_f32

__device__ __forceinline__ float fast_tanh(float a) {
    float e = __expf(2.0f * a);
    return 1.0f - 2.0f / (e + 1.0f);
}
__device__ __forceinline__ float bf_lo(unsigned u) { return __uint_as_float(u << 16); }
__device__ __forceinline__ float bf_hi(unsigned u) { return __uint_as_float(u & 0xffff0000u); }
__device__ __forceinline__ unsigned short bf_rne(float f) {
    unsigned u = __float_as_uint(f);
    u += 0x7fffu + ((u >> 16) & 1u);
    return (unsigned short)(u >> 16);
}
__device__ __forceinline__ unsigned pk_bf16(float lo, float hi) {
    union { __hip_bfloat162 h; unsigned u; } cv;
    cv.h = __float22bfloat162_rn(make_float2(lo, hi));
    return cv.u;
}
__device__ __forceinline__ bf8 cvt8(float4 a, float4 b) {
    union { bf8 v; unsigned u[4]; } r;
    r.u[0] = pk_bf16(a.x, a.y);
    r.u[1] = pk_bf16(a.z, a.w);
    r.u[2] = pk_bf16(b.x, b.y);
    r.u[3] = pk_bf16(b.z, b.w);
    return r.v;
}

// ---------------------------------------------------------------------------
// x (fp32 [256][512]) -> x_bf (bf16 packed dwords)
// ---------------------------------------------------------------------------
__global__ __launch_bounds__(256) void xbf_kernel(
    const float* __restrict__ x, unsigned* __restrict__ xb)
{
    int i = blockIdx.x * 256 + threadIdx.x;
    float2 v = *(const float2*)&x[(size_t)i * 2];
    xb[i] = pk_bf16(v.x, v.y);
}

// ---------------------------------------------------------------------------
// xproj via MFMA, software-pipelined, fused h1 = tanh(xp) epilogue.
// ---------------------------------------------------------------------------
__global__ __launch_bounds__(256) void xproj_mfma(
    const float* __restrict__ w_in, const float* __restrict__ bias,
    const short* __restrict__ xbf, unsigned short* __restrict__ xp,
    unsigned short* __restrict__ h1)
{
    const int tid = threadIdx.x, w = tid >> 6, lane = tid & 63;
    const int quad = lane >> 4, l16 = lane & 15;
    const int n0 = blockIdx.x * 16;
    const float* __restrict__ arow = &w_in[(size_t)(n0 + l16) * KDIM];

    f32x4 acc[4] = {};

    int ka = quad * 8;
    float4 a0 = *(const float4*)&arow[ka];
    float4 a1 = *(const float4*)&arow[ka + 4];
    bf8 bb[4];
#pragma unroll
    for (int j = 0; j < 4; ++j)
        bb[j] = *(const bf8*)&xbf[(size_t)(w * 64 + j * 16 + l16) * KDIM + ka];

    for (int it = 0; it < 16; ++it) {
        float4 na0{}, na1{}; bf8 nb[4] = {};
        if (it < 15) {
            const int nka = ka + 32;
            na0 = *(const float4*)&arow[nka];
            na1 = *(const float4*)&arow[nka + 4];
#pragma unroll
            for (int j = 0; j < 4; ++j)
                nb[j] = *(const bf8*)&xbf[(size_t)(w * 64 + j * 16 + l16) * KDIM + nka];
        }
        bf8 af = cvt8(a0, a1);
#pragma unroll
        for (int j = 0; j < 4; ++j)
            acc[j] = __builtin_amdgcn_mfma_f32_16x16x32_bf16(af, bb[j], acc[j], 0, 0, 0);
        a0 = na0; a1 = na1;
#pragma unroll
        for (int j = 0; j < 4; ++j) bb[j] = nb[j];
        ka += 32;
    }

#pragma unroll
    for (int j = 0; j < 4; ++j) {
        const int b = w * 64 + j * 16 + l16;
#pragma unroll
        for (int r = 0; r < 4; ++r) {
            const int n = n0 + quad * 4 + r;
            const float v = acc[j][r] + bias[n];
            xp[(size_t)n * BB + b] = bf_rne(v);
            h1[(size_t)n * BB + b] = bf_rne(fast_tanh(v));
        }
    }
}

// ---------------------------------------------------------------------------
// Cheap grid barrier: RELAXED monotonic arrival counter + gen flag (pure IC
// atomics, no implicit cache maintenance), leader-thread-only directed
// fences (release = wbl2, acquire = inv). bar[0]=arrivals, bar[1]=generation.
// ---------------------------------------------------------------------------
__device__ __forceinline__ void grid_barrier(unsigned* bar, unsigned nblk, int s)
{
    __syncthreads();                      // all block stores issued (L1 write-through -> L2)
    if (threadIdx.x == 0) {
        __builtin_amdgcn_fence(__ATOMIC_RELEASE, "agent");   // writeback this XCD's L2
        unsigned a = __hip_atomic_fetch_add(&bar[0], 1u,
                        __ATOMIC_RELAXED, __HIP_MEMORY_SCOPE_AGENT);
        if (a == nblk * (unsigned)(s + 1) - 1u) {
            __hip_atomic_store(&bar[1], (unsigned)(s + 1),
                               __ATOMIC_RELAXED, __HIP_MEMORY_SCOPE_AGENT);
        } else {
            while (__hip_atomic_load(&bar[1], __ATOMIC_RELAXED,
                                     __HIP_MEMORY_SCOPE_AGENT) < (unsigned)(s + 1))
                __builtin_amdgcn_s_sleep(2);
        }
        __builtin_amdgcn_fence(__ATOMIC_ACQUIRE, "agent");   // invalidate L1 + L2
    }
    __syncthreads();                      // others held until leader's inv done
}

// ---------------------------------------------------------------------------
// Step unit: ring-5 f2v register window, prefetch dist 2, packed-FMA math.
// ---------------------------------------------------------------------------
__device__ __forceinline__ void load_plane_f2(
    const unsigned* __restrict__ h32, int z, int y, int xx, int dof, f2v* w9)
{
#pragma unroll
    for (int j = 0; j < 9; ++j) {
        const int dz = j / 3 - 1, dy = j % 3 - 1;
        const int zz = z + dz, yy = y + dy;
        const bool valid = (xx >= 0) & (xx < CUBE) & (zz >= 0) & (zz < CUBE) &
                           (yy >= 0) & (yy < CUBE);   // wave-uniform
        unsigned v = 0u;
        if (valid) v = h32[(size_t)((zz * 24 + yy) * 24 + xx) * 128 + dof];
        f2v t; t.x = bf_lo(v); t.y = bf_hi(v);
        w9[j] = t;
    }
}

__device__ __forceinline__ void step_unit(
    const unsigned* __restrict__ hprev, const unsigned* __restrict__ xp,
    const float* __restrict__ wl, unsigned* __restrict__ hnext,
    int z, int y, int x0, int dof)
{
    f2v win[5][9];
    load_plane_f2(hprev, z, y, x0 - 1, dof, win[0]);
    load_plane_f2(hprev, z, y, x0,     dof, win[1]);
    load_plane_f2(hprev, z, y, x0 + 1, dof, win[2]);
    load_plane_f2(hprev, z, y, x0 + 2, dof, win[3]);

#pragma unroll
    for (int xi = 0; xi < 6; ++xi) {
        const int x = x0 + xi;
        if (xi <= 3)
            load_plane_f2(hprev, z, y, x + 3, dof, win[(xi + 4) % 5]);

        const int n = (z * 24 + y) * 24 + x;          // wave-uniform
        const float* __restrict__ wn = &wl[(size_t)n * 27];
        const unsigned xpv = xp[(size_t)n * 128 + dof];

        const f2v* pm = win[xi % 5];
        const f2v* pc = win[(xi + 1) % 5];
        const f2v* pp = win[(xi + 2) % 5];

        f2v a0; a0.x = bf_lo(xpv); a0.y = bf_hi(xpv);
        f2v a1 = {0.f, 0.f};
        f2v a2 = {0.f, 0.f};
#pragma unroll
        for (int jy = 0; jy < 3; ++jy) {
            {   const int j = jy;
                a0 += wn[3 * j] * pm[j] + wn[3 * j + 1] * pc[j] + wn[3 * j + 2] * pp[j]; }
            {   const int j = 3 + jy;
                a1 += wn[3 * j] * pm[j] + wn[3 * j + 1] * pc[j] + wn[3 * j + 2] * pp[j]; }
            {   const int j = 6 + jy;
                a2 += wn[3 * j] * pm[j] + wn[3 * j + 1] * pc[j] + wn[3 * j + 2] * pp[j]; }
        }
        const f2v s2 = a0 + a1 + a2;
        hnext[(size_t)n * 128 + dof] = pk_bf16(fast_tanh(s2.x), fast_tanh(s2.y));
    }
}

// ---------------------------------------------------------------------------
// Persistent steps. Grid 1152 x 256, 1 unit/wave (4608 units), 18 waves/CU.
// bid&7 = XCD z-slab; unit-in-slab = (bid>>3)*4 + wave.
// ---------------------------------------------------------------------------
__global__ __launch_bounds__(256, 5) void steps_persistent(
    unsigned* __restrict__ hA, unsigned* __restrict__ hB,
    const unsigned* __restrict__ xp, const float* __restrict__ wl,
    unsigned* bar)
{
    const int tid  = threadIdx.x;
    const int wv   = __builtin_amdgcn_readfirstlane(tid >> 6);
    const int lane = tid & 63;

    const int bid = blockIdx.x;           // 0..1151
    const int zhi = bid & 7;              // z slab
    const int u   = (bid >> 3) * 4 + wv;  // unit-in-slab 0..575

    const int y   = u % 24;
    const int r   = u / 24;               // 0..23
    const int xc  = r & 3;
    const int rr  = r >> 2;               // 0..5
    const int zlo = rr % 3;
    const int bh  = rr / 3;
    const int z   = zhi * 3 + zlo;
    const int x0  = xc * 6;
    const int dof = bh * 64 + lane;

    const unsigned* cur = hA;
    unsigned*       nxt = hB;
#pragma unroll 1
    for (int s = 0; s < 29; ++s) {
        step_unit(cur, xp, wl, nxt, z, y, x0, dof);
        if (s < 28) grid_barrier(bar, PBLK, s);
        const unsigned* t = cur; cur = nxt; nxt = (unsigned*)t;
    }
    // 29 steps from h1 in hA -> final state in hB
}

// ---------------------------------------------------------------------------
// Transpose h[k][b] -> hT[b][k] (bf16), 64x64 tiles via LDS.
// ---------------------------------------------------------------------------
__global__ __launch_bounds__(256) void transpose_kernel(
    const unsigned* __restrict__ h32, unsigned* __restrict__ hT32)
{
    __shared__ unsigned short T[64][66];
    const int tid = threadIdx.x;
    const int rr = tid >> 2, g = tid & 3;
    const int k0 = blockIdx.x * 64, b0 = blockIdx.y * 64;
#pragma unroll
    for (int i = 0; i < 8; ++i) {
        unsigned d = h32[(size_t)(k0 + rr) * 128 + b0 / 2 + g * 8 + i];
        const int bl = (g * 8 + i) * 2;
        T[bl][rr]     = (unsigned short)(d & 0xffffu);
        T[bl + 1][rr] = (unsigned short)(d >> 16);
    }
    __syncthreads();
#pragma unroll
    for (int i = 0; i < 8; ++i) {
        const int kl = (g * 8 + i) * 2;
        unsigned d = (unsigned)T[rr][kl] | ((unsigned)T[rr][kl + 1] << 16);
        hT32[(size_t)(b0 + rr) * (NN / 2) + k0 / 2 + g * 8 + i] = d;
    }
}

// ---------------------------------------------------------------------------
// Output GEMM via MFMA, split-K=16, software-pipelined (prefetch dist 1).
// ---------------------------------------------------------------------------
__global__ __launch_bounds__(256) void outgemm_mfma(
    const float* __restrict__ wout, const short* __restrict__ hT,
    float* __restrict__ part)
{
    const int tid = threadIdx.x, w = tid >> 6, lane = tid & 63;
    const int quad = lane >> 4, l16 = lane & 15;
    const int o0 = blockIdx.x * 32;
    const int kb = blockIdx.y * (NN / KS);
    const int b0 = w * 64;

    const int oa = o0 + l16, ob = o0 + 16 + l16;
    const bool av0 = oa < ODIM, av1 = ob < ODIM;
    const float* __restrict__ ar0 = &wout[(size_t)oa * NN];
    const float* __restrict__ ar1 = &wout[(size_t)ob * NN];
    const float4 z4 = {0.f, 0.f, 0.f, 0.f};

    f32x4 acc[2][4] = {};

    int ka = kb + quad * 8;
    float4 a00 = av0 ? *(const float4*)&ar0[ka]     : z4;
    float4 a01 = av0 ? *(const float4*)&ar0[ka + 4] : z4;
    float4 a10 = av1 ? *(const float4*)&ar1[ka]     : z4;
    float4 a11 = av1 ? *(const float4*)&ar1[ka + 4] : z4;
    bf8 bb[4];
#pragma unroll
    for (int j = 0; j < 4; ++j)
        bb[j] = *(const bf8*)&hT[(size_t)(b0 + j * 16 + l16) * NN + ka];

    for (int it = 0; it < 27; ++it) {
        float4 na00{}, na01{}, na10{}, na11{}; bf8 nb[4] = {};
        if (it < 26) {
            const int nka = ka + 32;
            na00 = av0 ? *(const float4*)&ar0[nka]     : z4;
            na01 = av0 ? *(const float4*)&ar0[nka + 4] : z4;
            na10 = av1 ? *(const float4*)&ar1[nka]     : z4;
            na11 = av1 ? *(const float4*)&ar1[nka + 4] : z4;
#pragma unroll
            for (int j = 0; j < 4; ++j)
                nb[j] = *(const bf8*)&hT[(size_t)(b0 + j * 16 + l16) * NN + nka];
        }
        bf8 af0 = cvt8(a00, a01);
        bf8 af1 = cvt8(a10, a11);
#pragma unroll
        for (int j = 0; j < 4; ++j) {
            acc[0][j] = __builtin_amdgcn_mfma_f32_16x16x32_bf16(af0, bb[j], acc[0][j], 0, 0, 0);
            acc[1][j] = __builtin_amdgcn_mfma_f32_16x16x32_bf16(af1, bb[j], acc[1][j], 0, 0, 0);
        }
        a00 = na00; a01 = na01; a10 = na10; a11 = na11;
#pragma unroll
        for (int j = 0; j < 4; ++j) bb[j] = nb[j];
        ka += 32;
    }

#pragma unroll
    for (int i = 0; i < 2; ++i)
#pragma unroll
        for (int j = 0; j < 4; ++j) {
            const int b = b0 + j * 16 + l16;
#pragma unroll
            for (int r = 0; r < 4; ++r) {
                const int o = o0 + i * 16 + quad * 4 + r;
                part[((size_t)blockIdx.y * 1024 + o) * BB + b] = acc[i][j][r];
            }
        }
}

__global__ __launch_bounds__(256) void reduce_kernel(
    const float* __restrict__ part, const float* __restrict__ bias,
    float* __restrict__ out)
{
    const int o = blockIdx.x, b = threadIdx.x;
    float s = bias[o];
#pragma unroll
    for (int kc = 0; kc < KS; ++kc)
        s += part[((size_t)kc * 1024 + o) * BB + b];
    out[(size_t)b * ODIM + o] = s;
}

extern "C" void kernel_launch(void* const* d_in, const int* in_sizes, int n_in,
                              void* d_out, int out_size, void* d_ws, size_t ws_size,
                              hipStream_t stream)
{
    const float* x       = (const float*)d_in[0];
    const float* w_in    = (const float*)d_in[1];
    const float* b_in    = (const float*)d_in[2];
    const float* w_local = (const float*)d_in[3];
    const float* w_out   = (const float*)d_in[4];
    const float* b_out   = (const float*)d_in[5];
    float* out = (float*)d_out;

    char* p = (char*)d_ws;
    unsigned short* xp_bf = (unsigned short*)p;          p += (size_t)NN * BB * 2;
    unsigned short* hA    = (unsigned short*)p;          p += (size_t)NN * BB * 2;
    unsigned short* hB    = (unsigned short*)p;          p += (size_t)NN * BB * 2;
    unsigned short* hT    = (unsigned short*)p;          p += (size_t)NN * BB * 2;
    unsigned short* x_bf  = (unsigned short*)p;          p += (size_t)BB * KDIM * 2;
    float*          part  = (float*)p;                   p += (size_t)KS * 1024 * BB * 4;
    unsigned*       bar   = (unsigned*)p;                // 2 dwords (arrivals, gen)

    hipMemsetAsync((void*)bar, 0, 2 * sizeof(unsigned), stream);

    xbf_kernel<<<256, 256, 0, stream>>>(x, (unsigned*)x_bf);
    xproj_mfma<<<864, 256, 0, stream>>>(w_in, b_in, (const short*)x_bf, xp_bf, hA);

    steps_persistent<<<PBLK, 256, 0, stream>>>(
        (unsigned*)hA, (unsigned*)hB, (const unsigned*)xp_bf, w_local, bar);

    // final state in hB
    transpose_kernel<<<dim3(216, 4), 256, 0, stream>>>((const unsigned*)hB, (unsigned*)hT);
    outgemm_mfma<<<dim3(32, KS), 256, 0, stream>>>(w_out, (const short*)hT, part);
    reduce_kernel<<<ODIM, 256, 0, stream>>>(part, b_out, out);
}

// Round 9
// 922.589 us; speedup vs baseline: 4.5704x; 4.4395x over previous
//
#include <hip/hip_runtime.h>
#include <hip/hip_bf16.h>

#define NN   13824     // 24^3 neurons
#define BB   256       // batch
#define KDIM 512       // input dim
#define ODIM 1000      // output dim
#define CUBE 24
#define KS   12        // out-gemm split-K (part 12.6MB aliases xp_bf+hA 14.2MB)

#define PC    26              // padded cube dim
#define PLANE (PC*PC)         // 676
#define PCUBE (PC*PC*PC)      // 17576 ushorts per col per buffer
#define COLU  17576           // col stride (ushorts)
#define BUFU  35152           // buffer stride (ushorts, 2 cols)
#define LDSB  140608          // 2 buffers * 2 cols * 17576 * 2B

typedef short bf8 __attribute__((ext_vector_type(8)));     // 8 bf16
typedef _Float16 h8 __attribute__((ext_vector_type(8)));   // 8 fp16
typedef _Float16 h2 __attribute__((ext_vector_type(2)));
typedef float f32x4 __attribute__((ext_vector_type(4)));

__device__ __forceinline__ float fast_tanh(float a) {
    float e = __expf(2.0f * a);
    return 1.0f - 2.0f / (e + 1.0f);
}
__device__ __forceinline__ float bf_lo(unsigned u) { return __uint_as_float(u << 16); }
__device__ __forceinline__ float bf_hi(unsigned u) { return __uint_as_float(u & 0xffff0000u); }
__device__ __forceinline__ unsigned short bf_rne(float f) {
    unsigned u = __float_as_uint(f);
    u += 0x7fffu + ((u >> 16) & 1u);
    return (unsigned short)(u >> 16);
}
__device__ __forceinline__ unsigned pk_bf16(float lo, float hi) {
    union { __hip_bfloat162 h; unsigned u; } cv;
    cv.h = __float22bfloat162_rn(make_float2(lo, hi));
    return cv.u;
}
__device__ __forceinline__ bf8 cvt8(float4 a, float4 b) {
    union { bf8 v; unsigned u[4]; } r;
    r.u[0] = pk_bf16(a.x, a.y); r.u[1] = pk_bf16(a.z, a.w);
    r.u[2] = pk_bf16(b.x, b.y); r.u[3] = pk_bf16(b.z, b.w);
    return r.v;
}
// ---- fp16 helpers ----
__device__ __forceinline__ unsigned short f16b(float a) {
    union { _Float16 h; unsigned short s; } c; c.h = (_Float16)a; return c.s;
}
__device__ __forceinline__ h2 u2h(unsigned u) {
    union { unsigned u; h2 h; } c; c.u = u; return c.h;
}
__device__ __forceinline__ float f16lo(unsigned u) { return (float)u2h(u).x; }
__device__ __forceinline__ float f16hi(unsigned u) { return (float)u2h(u).y; }
#if __has_builtin(__builtin_amdgcn_fdot2)
__device__ __forceinline__ float dot2(unsigned w, unsigned v, float acc) {
    return __builtin_amdgcn_fdot2(u2h(w), u2h(v), acc, false);
}
#else
__device__ __forceinline__ float dot2(unsigned w, unsigned v, float acc) {
    h2 W = u2h(w), V = u2h(v);
    return acc + (float)W.x * (float)V.x + (float)W.y * (float)V.y;
}
#endif
__device__ __forceinline__ h8 cvt8f(float4 a, float4 b) {
    union { h8 v; unsigned short s[8]; } r;
    r.s[0] = f16b(a.x); r.s[1] = f16b(a.y); r.s[2] = f16b(a.z); r.s[3] = f16b(a.w);
    r.s[4] = f16b(b.x); r.s[5] = f16b(b.y); r.s[6] = f16b(b.z); r.s[7] = f16b(b.w);
    return r.v;
}

// ---------------------------------------------------------------------------
// x (fp32 [256][512]) -> x_bf (bf16 packed dwords)
// ---------------------------------------------------------------------------
__global__ __launch_bounds__(256) void xbf_kernel(
    const float* __restrict__ x, unsigned* __restrict__ xb)
{
    int i = blockIdx.x * 256 + threadIdx.x;
    float2 v = *(const float2*)&x[(size_t)i * 2];
    xb[i] = pk_bf16(v.x, v.y);
}

// ---------------------------------------------------------------------------
// Weight repack for dot2 stencil: per row j=dzi*3+dyi (dzi,dyi in 0..2):
//   wab[j][n] = (w[3j], w[3j+1]) fp16 packed; wc[j][n] = w[3j+2] fp16.
// ---------------------------------------------------------------------------
__global__ __launch_bounds__(256) void wprep_kernel(
    const float* __restrict__ wl, unsigned* __restrict__ wab,
    unsigned short* __restrict__ wc)
{
    int n = blockIdx.x * 256 + threadIdx.x;   // grid 54*256 = 13824 exact
#pragma unroll
    for (int j = 0; j < 9; ++j) {
        float w0 = wl[n * 27 + 3 * j + 0];
        float w1 = wl[n * 27 + 3 * j + 1];
        float w2 = wl[n * 27 + 3 * j + 2];
        wab[j * NN + n] = (unsigned)f16b(w0) | ((unsigned)f16b(w1) << 16);
        wc[j * NN + n]  = f16b(w2);
    }
}

// ---------------------------------------------------------------------------
// xproj via MFMA. Writes: xpT fp16 [128 colpairs][NN] (for cube path),
// xp_bf bf16 [n][128] + h1 bf16 (for fallback path).
// ---------------------------------------------------------------------------
__global__ __launch_bounds__(256) void xproj_mfma(
    const float* __restrict__ w_in, const float* __restrict__ bias,
    const short* __restrict__ xbf, unsigned short* __restrict__ xpT_u,
    unsigned short* __restrict__ xp_bf, unsigned short* __restrict__ h1)
{
    const int tid = threadIdx.x, w = tid >> 6, lane = tid & 63;
    const int quad = lane >> 4, l16 = lane & 15;
    const int n0 = blockIdx.x * 16;
    const float* __restrict__ arow = &w_in[(size_t)(n0 + l16) * KDIM];

    f32x4 acc[4] = {};

    int ka = quad * 8;
    float4 a0 = *(const float4*)&arow[ka];
    float4 a1 = *(const float4*)&arow[ka + 4];
    bf8 bb[4];
#pragma unroll
    for (int j = 0; j < 4; ++j)
        bb[j] = *(const bf8*)&xbf[(size_t)(w * 64 + j * 16 + l16) * KDIM + ka];

    for (int it = 0; it < 16; ++it) {
        float4 na0{}, na1{}; bf8 nb[4] = {};
        if (it < 15) {
            const int nka = ka + 32;
            na0 = *(const float4*)&arow[nka];
            na1 = *(const float4*)&arow[nka + 4];
#pragma unroll
            for (int j = 0; j < 4; ++j)
                nb[j] = *(const bf8*)&xbf[(size_t)(w * 64 + j * 16 + l16) * KDIM + nka];
        }
        bf8 af = cvt8(a0, a1);
#pragma unroll
        for (int j = 0; j < 4; ++j)
            acc[j] = __builtin_amdgcn_mfma_f32_16x16x32_bf16(af, bb[j], acc[j], 0, 0, 0);
        a0 = na0; a1 = na1;
#pragma unroll
        for (int j = 0; j < 4; ++j) bb[j] = nb[j];
        ka += 32;
    }

#pragma unroll
    for (int j = 0; j < 4; ++j) {
        const int b = w * 64 + j * 16 + l16;
#pragma unroll
        for (int r = 0; r < 4; ++r) {
            const int n = n0 + quad * 4 + r;
            const float v = acc[j][r] + bias[n];
            xp_bf[(size_t)n * BB + b] = bf_rne(v);
            h1[(size_t)n * BB + b]    = bf_rne(fast_tanh(v));
            xpT_u[((size_t)(b >> 1) * NN + n) * 2 + (b & 1)] = f16b(v);
        }
    }
}

// ---------------------------------------------------------------------------
// THE CUBE KERNEL: block = 2 batch columns, whole padded 26^3 cube (fp16) in
// LDS, ping-pong buffers, all 29 steps with __syncthreads only. No inter-block
// communication ever (recurrence couples neurons, not batch). Stencil rows
// consumed via v_dot2_f32_f16 (packed fp16 taps, f32 accumulate). Borders are
// zero, written once. Grid 128 x 512, dynamic LDS 140608 B (1 block/CU).
// ---------------------------------------------------------------------------
__global__ __launch_bounds__(512) void cube_kernel(
    const unsigned* __restrict__ xpT,       // [128][NN] dwords (col0,col1) f16
    const unsigned* __restrict__ wab,       // [9][NN] (w0,w1) f16 packed
    const unsigned short* __restrict__ wc,  // [9][NN] w2 f16
    unsigned short* __restrict__ hT)        // [256][NN] f16 out
{
    extern __shared__ char smem[];
    unsigned*        sdw = (unsigned*)smem;
    unsigned short*  sus = (unsigned short*)smem;
    const int tid = threadIdx.x;
    const int cp  = blockIdx.x;            // column pair (cols 2cp, 2cp+1)

    // zero both buffers (borders stay zero forever)
    for (int i = tid; i < (LDSB / 4); i += 512) sdw[i] = 0u;
    __syncthreads();

    // init buf0 interior: h1 = tanh(xp)
#pragma unroll 1
    for (int k = 0; k < 14; ++k) {
        int p = tid + k * 512;
        if (p >= 6912) break;                       // wave-uniform
        int line = p / 12, xq = p - line * 12, x0 = 2 * xq;
        int z = line / 24, y = line - z * 24;
        int n0 = line * 24 + x0;
        uint2 xq2 = *(const uint2*)&xpT[(size_t)cp * NN + n0];
        int Pi = ((z + 1) * PC + (y + 1)) * PC + x0 + 1;
        sus[Pi]            = f16b(fast_tanh(f16lo(xq2.x)));
        sus[Pi + 1]        = f16b(fast_tanh(f16lo(xq2.y)));
        sus[COLU + Pi]     = f16b(fast_tanh(f16hi(xq2.x)));
        sus[COLU + Pi + 1] = f16b(fast_tanh(f16hi(xq2.y)));
    }
    __syncthreads();

    int cur = 0;
#pragma unroll 1
    for (int s = 0; s < 29; ++s) {
        const int curU = cur * BUFU;
        const int nxtU = curU ^ BUFU;
#pragma unroll 1
        for (int k = 0; k < 14; ++k) {
            int p = tid + k * 512;
            if (p >= 6912) break;                   // wave-uniform
            int line = p / 12, xq = p - line * 12, x0 = 2 * xq;
            int z = line / 24, y = line - z * 24;
            int n0 = line * 24 + x0;
            int pb = curU + (z * PC + y) * PC + x0; // (dz=-1,dy=-1) row base (even)

            uint2 xq2 = *(const uint2*)&xpT[(size_t)cp * NN + n0];
            float a00 = f16lo(xq2.x), a01 = f16hi(xq2.x);   // neuron n0, cols 0/1
            float a10 = f16lo(xq2.y), a11 = f16hi(xq2.y);   // neuron n0+1
#pragma unroll
            for (int j = 0; j < 9; ++j) {
                const int off = (j / 3) * PLANE + (j % 3) * PC;  // ushort units, even
                unsigned d0c0 = *(const unsigned*)&sus[pb + off];
                unsigned d1c0 = *(const unsigned*)&sus[pb + off + 2];
                unsigned d0c1 = *(const unsigned*)&sus[pb + off + COLU];
                unsigned d1c1 = *(const unsigned*)&sus[pb + off + COLU + 2];
                uint2 w2v = *(const uint2*)&wab[(size_t)j * NN + n0];
                unsigned wcd = *(const unsigned*)&wc[(size_t)j * NN + n0];
                unsigned wB0 = wcd & 0xffffu;       // (w2_n0, 0)
                unsigned wB1 = wcd >> 16;           // (w2_n1, 0)
                // n0: taps d0 = (h(x-1),h(x)), d1 = (h(x+1),h(x+2))
                a00 = dot2(w2v.x, d0c0, a00); a00 = dot2(wB0, d1c0, a00);
                a01 = dot2(w2v.x, d0c1, a01); a01 = dot2(wB0, d1c1, a01);
                // n1: shifted windows
                unsigned s1c0 = __builtin_amdgcn_alignbit(d1c0, d0c0, 16); // (h(x),h(x+1))
                unsigned s3c0 = d1c0 >> 16;                                // (h(x+2),0)
                unsigned s1c1 = __builtin_amdgcn_alignbit(d1c1, d0c1, 16);
                unsigned s3c1 = d1c1 >> 16;
                a10 = dot2(w2v.y, s1c0, a10); a10 = dot2(wB1, s3c0, a10);
                a11 = dot2(w2v.y, s1c1, a11); a11 = dot2(wB1, s3c1, a11);
            }
            int Pw = nxtU + (pb - curU) + PLANE + PC + 1;   // interior of x0 in nxt
            sus[Pw]            = f16b(fast_tanh(a00));
            sus[Pw + 1]        = f16b(fast_tanh(a10));
            sus[Pw + COLU]     = f16b(fast_tanh(a01));
            sus[Pw + COLU + 1] = f16b(fast_tanh(a11));
        }
        __syncthreads();
        cur ^= 1;
    }

    // final state in buffer `cur` -> hT (f16, coalesced 2B stores)
    const int fU = cur * BUFU;
    for (int n = tid; n < NN; n += 512) {
        int z = n / 576, r = n - z * 576, y = r / 24, x = r - y * 24;
        int P = fU + ((z + 1) * PC + (y + 1)) * PC + x + 1;
        hT[(size_t)(2 * cp) * NN + n]     = sus[P];
        hT[(size_t)(2 * cp + 1) * NN + n] = sus[P + COLU];
    }
}

// ---------------------------------------------------------------------------
// FALLBACK: R5 per-step kernel (bf16, 29 launches) + transpose w/ bf16->f16.
// ---------------------------------------------------------------------------
__device__ __forceinline__ void load_plane_f2(
    const unsigned* __restrict__ h32, int z, int y, int xx, int dof, float2* w9)
{
#pragma unroll
    for (int j = 0; j < 9; ++j) {
        const int dz = j / 3 - 1, dy = j % 3 - 1;
        const int zz = z + dz, yy = y + dy;
        const bool valid = (xx >= 0) & (xx < CUBE) & (zz >= 0) & (zz < CUBE) &
                           (yy >= 0) & (yy < CUBE);
        unsigned v = 0u;
        if (valid) v = h32[(size_t)((zz * 24 + yy) * 24 + xx) * 128 + dof];
        w9[j] = make_float2(bf_lo(v), bf_hi(v));
    }
}

__global__ __launch_bounds__(128) void step_kernel(
    const unsigned* __restrict__ hprev, const unsigned* __restrict__ xp,
    const float* __restrict__ wl, unsigned* __restrict__ hnext)
{
    const int tid  = threadIdx.x;
    const int wv   = __builtin_amdgcn_readfirstlane(tid >> 6);
    const int lane = tid & 63;
    const int bid   = blockIdx.x;
    const int zhi   = bid & 7;
    const int inner = bid >> 3;
    const int y     = inner % 24;
    const int r     = inner / 24;
    const int xc    = r & 3;
    const int zlo   = r >> 2;
    const int z     = zhi * 3 + zlo;
    const int x0    = xc * 6;
    const int dof   = wv * 64 + lane;

    float2 win[5][9];
    load_plane_f2(hprev, z, y, x0 - 1, dof, win[0]);
    load_plane_f2(hprev, z, y, x0,     dof, win[1]);
    load_plane_f2(hprev, z, y, x0 + 1, dof, win[2]);
    load_plane_f2(hprev, z, y, x0 + 2, dof, win[3]);

#pragma unroll
    for (int xi = 0; xi < 6; ++xi) {
        const int x = x0 + xi;
        if (xi <= 3) load_plane_f2(hprev, z, y, x + 3, dof, win[(xi + 4) % 5]);
        const int n = (z * 24 + y) * 24 + x;
        const float* __restrict__ wn = &wl[(size_t)n * 27];
        const unsigned xpv = xp[(size_t)n * 128 + dof];
        float2 acc = make_float2(bf_lo(xpv), bf_hi(xpv));
        const float2* pm = win[xi % 5];
        const float2* pc = win[(xi + 1) % 5];
        const float2* pp = win[(xi + 2) % 5];
#pragma unroll
        for (int j = 0; j < 9; ++j) {
            const float w0 = wn[3 * j], w1 = wn[3 * j + 1], w2 = wn[3 * j + 2];
            acc.x += w0 * pm[j].x + w1 * pc[j].x + w2 * pp[j].x;
            acc.y += w0 * pm[j].y + w1 * pc[j].y + w2 * pp[j].y;
        }
        hnext[(size_t)n * 128 + dof] = pk_bf16(fast_tanh(acc.x), fast_tanh(acc.y));
    }
}

__global__ __launch_bounds__(256) void transpose_cvt(
    const unsigned* __restrict__ h32, unsigned* __restrict__ hT32)
{
    __shared__ unsigned short T[64][66];
    const int tid = threadIdx.x;
    const int rr = tid >> 2, g = tid & 3;
    const int k0 = blockIdx.x * 64, b0 = blockIdx.y * 64;
#pragma unroll
    for (int i = 0; i < 8; ++i) {
        unsigned d = h32[(size_t)(k0 + rr) * 128 + b0 / 2 + g * 8 + i];
        const int bl = (g * 8 + i) * 2;
        T[bl][rr]     = (unsigned short)(d & 0xffffu);
        T[bl + 1][rr] = (unsigned short)(d >> 16);
    }
    __syncthreads();
#pragma unroll
    for (int i = 0; i < 8; ++i) {
        const int kl = (g * 8 + i) * 2;
        float fa = __uint_as_float((unsigned)T[rr][kl] << 16);
        float fb = __uint_as_float((unsigned)T[rr][kl + 1] << 16);
        hT32[(size_t)(b0 + rr) * (NN / 2) + k0 / 2 + g * 8 + i] =
            (unsigned)f16b(fa) | ((unsigned)f16b(fb) << 16);
    }
}

// ---------------------------------------------------------------------------
// Output GEMM via f16 MFMA, split-K=12, software-pipelined.
// ---------------------------------------------------------------------------
__global__ __launch_bounds__(256) void outgemm_mfma(
    const float* __restrict__ wout, const _Float16* __restrict__ hT,
    float* __restrict__ part)
{
    const int tid = threadIdx.x, w = tid >> 6, lane = tid & 63;
    const int quad = lane >> 4, l16 = lane & 15;
    const int o0 = blockIdx.x * 32;
    const int kb = blockIdx.y * (NN / KS);
    const int b0 = w * 64;

    const int oa = o0 + l16, ob = o0 + 16 + l16;
    const bool av0 = oa < ODIM, av1 = ob < ODIM;
    const float* __restrict__ ar0 = &wout[(size_t)oa * NN];
    const float* __restrict__ ar1 = &wout[(size_t)ob * NN];
    const float4 z4 = {0.f, 0.f, 0.f, 0.f};

    f32x4 acc[2][4] = {};

    int ka = kb + quad * 8;
    float4 a00 = av0 ? *(const float4*)&ar0[ka]     : z4;
    float4 a01 = av0 ? *(const float4*)&ar0[ka + 4] : z4;
    float4 a10 = av1 ? *(const float4*)&ar1[ka]     : z4;
    float4 a11 = av1 ? *(const float4*)&ar1[ka + 4] : z4;
    h8 bb[4];
#pragma unroll
    for (int j = 0; j < 4; ++j)
        bb[j] = *(const h8*)&hT[(size_t)(b0 + j * 16 + l16) * NN + ka];

    const int ITER = (NN / KS) / 32;    // 36
    for (int it = 0; it < ITER; ++it) {
        float4 na00{}, na01{}, na10{}, na11{}; h8 nb[4] = {};
        if (it < ITER - 1) {
            const int nka = ka + 32;
            na00 = av0 ? *(const float4*)&ar0[nka]     : z4;
            na01 = av0 ? *(const float4*)&ar0[nka + 4] : z4;
            na10 = av1 ? *(const float4*)&ar1[nka]     : z4;
            na11 = av1 ? *(const float4*)&ar1[nka + 4] : z4;
#pragma unroll
            for (int j = 0; j < 4; ++j)
                nb[j] = *(const h8*)&hT[(size_t)(b0 + j * 16 + l16) * NN + nka];
        }
        h8 af0 = cvt8f(a00, a01);
        h8 af1 = cvt8f(a10, a11);
#pragma unroll
        for (int j = 0; j < 4; ++j) {
            acc[0][j] = __builtin_amdgcn_mfma_f32_16x16x32_f16(af0, bb[j], acc[0][j], 0, 0, 0);
            acc[1][j] = __builtin_amdgcn_mfma_f32_16x16x32_f16(af1, bb[j], acc[1][j], 0, 0, 0);
        }
        a00 = na00; a01 = na01; a10 = na10; a11 = na11;
#pragma unroll
        for (int j = 0; j < 4; ++j) bb[j] = nb[j];
        ka += 32;
    }

#pragma unroll
    for (int i = 0; i < 2; ++i)
#pragma unroll
        for (int j = 0; j < 4; ++j) {
            const int b = b0 + j * 16 + l16;
#pragma unroll
            for (int r = 0; r < 4; ++r) {
                const int o = o0 + i * 16 + quad * 4 + r;
                part[((size_t)blockIdx.y * 1024 + o) * BB + b] = acc[i][j][r];
            }
        }
}

__global__ __launch_bounds__(256) void reduce_kernel(
    const float* __restrict__ part, const float* __restrict__ bias,
    float* __restrict__ out)
{
    const int o = blockIdx.x, b = threadIdx.x;
    float s = bias[o];
#pragma unroll
    for (int kc = 0; kc < KS; ++kc)
        s += part[((size_t)kc * 1024 + o) * BB + b];
    out[(size_t)b * ODIM + o] = s;
}

extern "C" void kernel_launch(void* const* d_in, const int* in_sizes, int n_in,
                              void* d_out, int out_size, void* d_ws, size_t ws_size,
                              hipStream_t stream)
{
    const float* x       = (const float*)d_in[0];
    const float* w_in    = (const float*)d_in[1];
    const float* b_in    = (const float*)d_in[2];
    const float* w_local = (const float*)d_in[3];
    const float* w_out   = (const float*)d_in[4];
    const float* b_out   = (const float*)d_in[5];
    float* out = (float*)d_out;

    char* p = (char*)d_ws;
    unsigned*       xpT   = (unsigned*)p;        p += (size_t)128 * NN * 4;   // 7.08 MB
    unsigned short* hT    = (unsigned short*)p;  p += (size_t)256 * NN * 2;   // 7.08 MB
    unsigned short* x_bf  = (unsigned short*)p;  p += (size_t)BB * KDIM * 2;  // 0.26 MB
    unsigned*       wab   = (unsigned*)p;        p += (size_t)9 * NN * 4;     // 0.50 MB
    unsigned short* wc    = (unsigned short*)p;  p += (size_t)9 * NN * 2;     // 0.25 MB
    unsigned short* xp_bf = (unsigned short*)p;  p += (size_t)NN * BB * 2;    // 7.08 MB
    unsigned short* hA    = (unsigned short*)p;  p += (size_t)NN * BB * 2;    // 7.08 MB
    unsigned short* hB    = (unsigned short*)p;  p += (size_t)NN * BB * 2;    // 7.08 MB
    float* part = (float*)xp_bf;   // 12*1024*256*4 = 12.6 MB <= xp_bf+hA (14.2 MB)

    xbf_kernel<<<256, 256, 0, stream>>>(x, (unsigned*)x_bf);
    wprep_kernel<<<54, 256, 0, stream>>>(w_local, wab, wc);
    xproj_mfma<<<864, 256, 0, stream>>>(w_in, b_in, (const short*)x_bf,
                                        (unsigned short*)xpT, xp_bf, hA);

    bool fast = hipFuncSetAttribute((const void*)cube_kernel,
        hipFuncAttributeMaxDynamicSharedMemorySize, LDSB) == hipSuccess;

    if (fast) {
        cube_kernel<<<128, 512, LDSB, stream>>>(xpT, wab, wc, hT);
    } else {
        const unsigned* hp = (const unsigned*)hA;
        unsigned* hn = (unsigned*)hB;
        for (int s = 0; s < 29; ++s) {     // 29 odd -> final in hB
            step_kernel<<<2304, 128, 0, stream>>>(hp, (const unsigned*)xp_bf, w_local, hn);
            unsigned* t = (unsigned*)hp; hp = hn; hn = t;
        }
        transpose_cvt<<<dim3(216, 4), 256, 0, stream>>>((const unsigned*)hB, (unsigned*)hT);
    }

    outgemm_mfma<<<dim3(32, KS), 256, 0, stream>>>(w_out, (const _Float16*)hT, part);
    reduce_kernel<<<ODIM, 256, 0, stream>>>(part, b_out, out);
}